// Round 23
// baseline (278.947 us; speedup 1.0000x reference)
//
#include <hip/hip_runtime.h>
#include <math.h>

// Problem constants
#define B_ 8
#define N_ 128
#define H_ 64
#define MH_ 128
#define D_ 4
#define TSTEPS 12
#define NBLK 256          // 1 block/CU x 256 CU -> all co-resident

typedef __attribute__((ext_vector_type(8))) short bf16x8;
typedef __attribute__((ext_vector_type(4))) float f32x4;
typedef __attribute__((ext_vector_type(4))) unsigned u32x4;
typedef unsigned uint32;

__device__ __forceinline__ float fast_tanh(float x) {
    float t = __builtin_amdgcn_exp2f(x * 2.8853900817779268f);
    return 1.0f - 2.0f * __builtin_amdgcn_rcpf(t + 1.0f);
}
__device__ __forceinline__ float fast_sigmoid(float x) {
    float t = __builtin_amdgcn_exp2f(x * -1.4426950408889634f);
    return __builtin_amdgcn_rcpf(1.0f + t);
}
__device__ __forceinline__ unsigned short f2bf(float x) {
    unsigned u = __builtin_bit_cast(unsigned, x);
    u += 0x7fffu + ((u >> 16) & 1u);   // RNE
    return (unsigned short)(u >> 16);
}
// packed bf16 pair: low16 = bf16(lo), high16 = bf16(hi); RNE (same as f2bf)
__device__ __forceinline__ uint32 cvtpk(float lo, float hi) {
    uint32 r;
    asm("v_cvt_pk_bf16_f32 %0, %1, %2" : "=v"(r) : "v"(lo), "v"(hi));
    return r;
}

// ---------------- workspace layout (uint32 units) ----------------
// P(t+1) in its own per-step buffer (t = 0..10): consumer addresses are first
// touched only after the producer's write-through lands -> plain coalesced
// loads are fresh, no fences. Producers publish via relaxed agent-scope
// (write-through) atomic stores. Sync per (batch, 32-row i-window),
// ONE global signal per producing block per step (LDS last-arriver).
constexpr int PB_STRIDE = 65536;              // [8][128][64] uints per step-buffer
constexpr int CTRLu = 11 * PB_STRIDE;         // cnt[8][4] @ stride 16; SSE @ +512; DONE @ +513
constexpr int CTRL_BYTES = (32 * 16 + 2) * 4;

__global__ __launch_bounds__(1024, 4) void fused(
    const float* __restrict__ A, const float* __restrict__ X,
    const float* __restrict__ Wm1, const float* __restrict__ bm1,
    const float* __restrict__ Wm2, const float* __restrict__ bm2,
    const float* __restrict__ Wir, const float* __restrict__ bir,
    const float* __restrict__ Wii, const float* __restrict__ bii,
    const float* __restrict__ Win, const float* __restrict__ bin_,
    const float* __restrict__ Whr, const float* __restrict__ Whi, const float* __restrict__ Whh,
    const float* __restrict__ Wmr, const float* __restrict__ Wmi, const float* __restrict__ Wmn,
    const float* __restrict__ Wo1, const float* __restrict__ bo1,
    const float* __restrict__ Wo2, const float* __restrict__ bo2,
    const float* __restrict__ Wo3, const float* __restrict__ bo3,
    const float* __restrict__ lsg,
    uint32* wsU, float* __restrict__ out)
{
    __shared__ __align__(16) unsigned short wm2f[8192];  // 16 KB Wm2 MFMA B-fragments
    __shared__ __align__(16) float WamL[12288];          // 48 KB [k][192] Wmr|Wmi|Wmn
    __shared__ __align__(16) float Wm1L[16384];          // 64 KB [k][128] (full Wm1)
    __shared__ float Qj[4][128], apRow[4][128], rs[128], bmS[128];
    __shared__ float aggbuf[4][4][64];                   // rowsum partials at init / MLP scratch
    __shared__ float sAgg[4][64], sAm[4][192], sHP[4][192];
    __shared__ float sHist[TSTEPS][4][64];               // 12 KB: h(t) history
    __shared__ float sX[4][4];
    __shared__ int pubCnt;                               // LDS publish coordinator

    const int bid = blockIdx.x, tid = threadIdx.x;
    const int b = bid >> 5;                 // batch
    const int j0 = (bid & 31) << 2;         // block owns rows j0..j0+3
    const int wave = tid >> 6, lane = tid & 63;
    const int jj = wave >> 2;               // which of the 4 j-rows (phase A)
    const int wvj = wave & 3;               // i-window index (phase A)
    const int l15 = lane & 15, g = lane >> 4;
    const int myI0 = wvj * 32;

    int*   cntBase = (int*)(wsU + CTRLu);
    int*   cntW    = cntBase + (b * 4 + wvj) * 16;          // window this wave CONSUMES
    int*   cntPub  = cntBase + (b * 4 + (j0 >> 5)) * 16;    // window this block PRODUCES
    float* sseG    = (float*)(wsU + CTRLu + 512);
    int*   doneG   = (int*)(wsU + CTRLu + 513);
    const float* Ab = A + b * 16384;

    // ================= init (fully block-local) =================
    {   // rowsum_i: 1024 threads, 8 chunks of 16 j each
        int i = tid & 127, q = tid >> 7;
        float part = 0.f;
        int jlo = q * 16;
        #pragma unroll 4
        for (int j2 = jlo; j2 < jlo + 16; ++j2)
            if (j2 != i)
                part += fast_sigmoid(0.5f * (Ab[i * 128 + j2] + Ab[j2 * 128 + i]));
        ((float*)aggbuf)[q * 128 + i] = part;   // [8][128] view
    }
    __syncthreads();
    if (tid < 128) {
        const float* f = (const float*)aggbuf;
        float s = 0.f;
        #pragma unroll
        for (int c = 0; c < 8; ++c) s += f[c * 128 + tid];
        rs[tid] = s + 1e-6f;
        bmS[tid] = bm1[tid];
    }
    __syncthreads();
    if (tid < 512) {    // apRow[h][i] = s(i, j0+h) / rowsum_i
        int i = tid & 127, h = tid >> 7, jc = j0 + h;
        float s = (i == jc) ? 0.f
                : fast_sigmoid(0.5f * (Ab[i * 128 + jc] + Ab[jc * 128 + i]));
        apRow[h][i] = s / rs[i];
    }
    for (int idx = tid; idx < 8192; idx += 1024) {   // pack Wm2 -> bf16 B-fragments
        int kt = idx >> 11, nt = (idx >> 9) & 3, ln = (idx >> 3) & 63, e = idx & 7;
        int k = kt * 32 + (ln >> 4) * 8 + e, n = nt * 16 + (ln & 15);
        wm2f[idx] = f2bf(Wm2[k * 64 + n]);
    }
    for (int idx = tid; idx < 12288; idx += 1024) {  // WamL[k*192+c] fp32
        int k = idx / 192, c = idx % 192;
        WamL[idx] = ((c < 64) ? Wmr : (c < 128) ? Wmi : Wmn)[k * 64 + (c & 63)];
    }
    for (int idx = tid; idx < 16384; idx += 1024)    // Wm1L direct copy [128][128]
        Wm1L[idx] = Wm1[idx];
    if (tid < 512) Qj[tid >> 7][tid & 127] = 0.f;
    if (tid < 768) sHP[tid / 192][tid % 192] = 0.f;
    if (tid < 256) sAgg[tid >> 6][tid & 63] = 0.f;   // atomics accumulate into zeroed sAgg
    if (tid == 0) pubCnt = 0;
    __syncthreads();

    // ================= time loop =================
    for (int t = 0; t < TSTEPS; ++t) {
        const uint32* Psrc = wsU + (t - 1) * PB_STRIDE + b * 8192;  // valid for t>0
        u32x4 pv[4][2];
        if (t > 0) {
            const int target = 8 * t;   // 8 producing blocks x 1 signal per window
            int guard = 0;
            while (__hip_atomic_load(cntW, __ATOMIC_RELAXED, __HIP_MEMORY_SCOPE_AGENT) < target
                   && guard < (1 << 20)) {
                __builtin_amdgcn_s_sleep(1);
                ++guard;
            }
            __builtin_amdgcn_fence(__ATOMIC_ACQUIRE, "workgroup");  // no hoisting of P loads
            // issue ALL 8 fragment loads back-to-back (latencies overlap), one wait.
            // inline asm so the compiler cannot sink them into the tanh loop.
            #pragma unroll
            for (int kt = 0; kt < 4; ++kt)
                #pragma unroll
                for (int mt = 0; mt < 2; ++mt) {
                    int row = myI0 + mt * 16 + l15;
                    const uint32* ap = Psrc + row * 64 + kt * 16 + g * 4;
                    asm volatile("global_load_dwordx4 %0, %1, off"
                                 : "=v"(pv[kt][mt]) : "v"(ap) : "memory");
                }
            asm volatile("s_waitcnt vmcnt(0)" ::: "memory");
        }

        // ===== phase A: msg = tanh(tanh(P_i + Q_j) @ Wm2 + bm2), A-weighted agg =====
        f32x4 acc[2][4];
        #pragma unroll
        for (int mt = 0; mt < 2; ++mt)
            #pragma unroll
            for (int nt = 0; nt < 4; ++nt) {
                f32x4 z = {0.f, 0.f, 0.f, 0.f};
                acc[mt][nt] = z;
            }
        #pragma unroll
        for (int kt = 0; kt < 4; ++kt) {
            int k0 = kt * 32 + g * 8;
            bf16x8 bf[4];
            #pragma unroll
            for (int nt = 0; nt < 4; ++nt)
                bf[nt] = *(const bf16x8*)&wm2f[((kt * 4 + nt) * 64 + lane) << 3];
            f32x4 qa = *(const f32x4*)&Qj[jj][k0];
            f32x4 qb = *(const f32x4*)&Qj[jj][k0 + 4];
            bf16x8 af[2];
            #pragma unroll
            for (int mt = 0; mt < 2; ++mt) {
                float pe[8];
                if (t > 0) {    // registers, preloaded above
                    u32x4 p4 = pv[kt][mt];
                    #pragma unroll
                    for (int c = 0; c < 4; ++c) {
                        pe[2 * c]     = __builtin_bit_cast(float, p4[c] << 16);
                        pe[2 * c + 1] = __builtin_bit_cast(float, p4[c] & 0xFFFF0000u);
                    }
                } else {        // P(0) rows are all bm1 (h0 = 0)
                    #pragma unroll
                    for (int e = 0; e < 8; ++e) pe[e] = bmS[k0 + e];
                }
                float tv[8];
                #pragma unroll
                for (int e = 0; e < 4; ++e) {
                    tv[e]     = fast_tanh(pe[e] + qa[e]);
                    tv[4 + e] = fast_tanh(pe[4 + e] + qb[e]);
                }
                u32x4 aw;
                aw[0] = cvtpk(tv[0], tv[1]); aw[1] = cvtpk(tv[2], tv[3]);
                aw[2] = cvtpk(tv[4], tv[5]); aw[3] = cvtpk(tv[6], tv[7]);
                af[mt] = __builtin_bit_cast(bf16x8, aw);
            }
            #pragma unroll
            for (int mt = 0; mt < 2; ++mt)
                #pragma unroll
                for (int nt = 0; nt < 4; ++nt)
                    acc[mt][nt] = __builtin_amdgcn_mfma_f32_16x16x32_bf16(af[mt], bf[nt], acc[mt][nt], 0, 0, 0);
        }
        {
            float bmv[4];
            #pragma unroll
            for (int nt = 0; nt < 4; ++nt) bmv[nt] = bm2[nt * 16 + l15];
            float pagg[4] = {0.f, 0.f, 0.f, 0.f};
            #pragma unroll
            for (int mt = 0; mt < 2; ++mt) {
                float w[4];
                #pragma unroll
                for (int v = 0; v < 4; ++v) w[v] = apRow[jj][myI0 + mt * 16 + g * 4 + v];
                #pragma unroll
                for (int nt = 0; nt < 4; ++nt)
                    #pragma unroll
                    for (int v = 0; v < 4; ++v)
                        pagg[nt] += w[v] * fast_tanh(acc[mt][nt][v] + bmv[nt]);
            }
            #pragma unroll
            for (int nt = 0; nt < 4; ++nt) {
                pagg[nt] += __shfl_xor(pagg[nt], 16);
                pagg[nt] += __shfl_xor(pagg[nt], 32);
            }
            if (lane < 16)
                #pragma unroll
                for (int nt = 0; nt < 4; ++nt)
                    atomicAdd(&sAgg[jj][nt * 16 + lane], pagg[nt]);
        }
        __syncthreads();   // b1: sAgg complete

        // ===== am GEMV (6 waves) + X load on idle lanes =====
        if (tid < 384) {
            int pr2 = tid / 192, c = tid % 192;
            int ar0 = pr2 * 2, ar1 = ar0 + 1;
            float a0 = 0.f, a1 = 0.f;
            #pragma unroll 8
            for (int k = 0; k < 64; ++k) {
                float w = WamL[k * 192 + c];
                a0 += sAgg[ar0][k] * w; a1 += sAgg[ar1][k] * w;
            }
            sAm[ar0][c] = a0; sAm[ar1][c] = a1;
        } else if (tid >= 960 && tid < 976) {   // X load
            int q = tid - 960;
            int r = q >> 2, d = q & 3, jrow = j0 + r;
            sX[r][d] = X[((b * 13 + t) * 128 + jrow) * 4 + d];
        }
        __syncthreads();   // b2: sAm + sX ready

        if (tid < 256) {   // GRU gates, one row per 64-thread group; h -> history
            int r = tid >> 6, o = tid & 63;
            float xr = bir[o], xi = bii[o], xn = bin_[o];
            #pragma unroll
            for (int d = 0; d < 4; ++d) {
                float xv = sX[r][d];
                xr += xv * Wir[d * 64 + o];
                xi += xv * Wii[d * 64 + o];
                xn += xv * Win[d * 64 + o];
            }
            float hprev = (t > 0) ? sHist[t - 1][r][o] : 0.f;
            float rr = fast_sigmoid(xr + sHP[r][o]       + sAm[r][o]);
            float ig = fast_sigmoid(xi + sHP[r][64 + o]  + sAm[r][64 + o]);
            float nn = fast_tanh  (xn + rr * sHP[r][128 + o] + sAm[r][128 + o]);
            sHist[t][r][o] = (1.0f - ig) * nn + ig * hprev;
        }
        __syncthreads();   // b3: h(t) ready

        // ===== GEMV phase: P' (8 waves, k-split) / Q' (2 waves) / HP' (6 waves) =====
        if (t < TSTEPS - 1) {
            if (wave < 4 || (wave >= 8 && wave < 12)) {       // P' k-split + publish
                int p = (wave >= 8) ? 1 : 0;
                int wl = wave & 3;
                int rr0 = p * 2, rr1 = rr0 + 1;
                int o = wl * 32 + (lane & 31);                // 0..127
                int klo = (lane >> 5) << 5;                   // 0 or 32
                float a0 = 0.f, a1 = 0.f;
                #pragma unroll 8
                for (int k = klo; k < klo + 32; ++k) {
                    float w = Wm1L[k * 128 + o];
                    a0 += sHist[t][rr0][k] * w; a1 += sHist[t][rr1][k] * w;
                }
                a0 += __shfl_xor(a0, 32);
                a1 += __shfl_xor(a1, 32);
                if (lane < 32) {
                    a0 += bmS[o]; a1 += bmS[o];
                    uint32 u0 = cvtpk(a0, __shfl_down(a0, 1));
                    uint32 u1 = cvtpk(a1, __shfl_down(a1, 1));
                    if ((o & 1) == 0) {
                        uint32* base = wsU + t * PB_STRIDE + b * 8192;
                        __hip_atomic_store(base + (j0 + rr0) * 64 + (o >> 1), u0,
                                           __ATOMIC_RELAXED, __HIP_MEMORY_SCOPE_AGENT);
                        __hip_atomic_store(base + (j0 + rr1) * 64 + (o >> 1), u1,
                                           __ATOMIC_RELAXED, __HIP_MEMORY_SCOPE_AGENT);
                    }
                }
                asm volatile("s_waitcnt vmcnt(0)" ::: "memory");   // wave's stores landed
                if (lane == 0) {
                    int prev = __hip_atomic_fetch_add(&pubCnt, 1, __ATOMIC_RELAXED,
                                                      __HIP_MEMORY_SCOPE_WORKGROUP);
                    if (prev == 8 * t + 7)   // last of 8 P' waves this step
                        __hip_atomic_fetch_add(cntPub, 1, __ATOMIC_RELAXED,
                                               __HIP_MEMORY_SCOPE_AGENT);
                }
            } else if (wave == 4 || wave == 12) {             // Q' (2 outputs/thread)
                int p = (wave == 12) ? 1 : 0;
                int rr0 = p * 2, rr1 = rr0 + 1;
                #pragma unroll
                for (int h2 = 0; h2 < 2; ++h2) {
                    int oo = lane + h2 * 64;
                    float a0 = 0.f, a1 = 0.f;
                    #pragma unroll 8
                    for (int k = 0; k < 64; ++k) {
                        float w = Wm1L[(64 + k) * 128 + oo];
                        a0 += sHist[t][rr0][k] * w; a1 += sHist[t][rr1][k] * w;
                    }
                    Qj[rr0][oo] = a0; Qj[rr1][oo] = a1;
                }
                if (wave == 12) {   // zero sAgg for t+1
                    #pragma unroll
                    for (int r = 0; r < 4; ++r) sAgg[r][lane] = 0.f;
                }
            } else {                                          // HP': waves 5-7 / 13-15
                int p = (wave >= 13) ? 1 : 0;
                int rr0 = p * 2, rr1 = rr0 + 1;
                int c = p ? (tid - 832) : (tid - 320);        // 0..191
                const float* W = (c < 64) ? Whr : (c < 128) ? Whi : Whh;
                int oc = c & 63;
                float a0 = 0.f, a1 = 0.f;
                #pragma unroll 8
                for (int k = 0; k < 64; ++k) {
                    float w = W[k * 64 + oc];
                    a0 += sHist[t][rr0][k] * w; a1 += sHist[t][rr1][k] * w;
                }
                sHP[rr0][c] = a0; sHP[rr1][c] = a1;
            }
        }
        __syncthreads();   // b4
    }

    // ================= deferred output MLP + SSE (off the recurrence path) =================
    float ssePart = 0.f;
    {
        float* scratch = &((float*)aggbuf)[wave * 64];   // [16][64] per-wave view
        #pragma unroll
        for (int inst = 0; inst < 3; ++inst) {
            int idx = wave + (inst << 4);      // 0..47 = (t, r)
            int tt = idx >> 2, r = idx & 3;
            // layer 1
            float a = bo1[lane];
            #pragma unroll 8
            for (int k = 0; k < 64; ++k) a += sHist[tt][r][k] * Wo1[k * 64 + lane];
            scratch[lane] = fmaxf(a, 0.f);
            asm volatile("s_waitcnt lgkmcnt(0)" ::: "memory");
            __builtin_amdgcn_sched_barrier(0);
            // layer 2
            float a2 = bo2[lane];
            #pragma unroll 8
            for (int k = 0; k < 64; ++k) a2 += scratch[k] * Wo2[k * 64 + lane];
            scratch[lane] = fmaxf(a2, 0.f);
            asm volatile("s_waitcnt lgkmcnt(0)" ::: "memory");
            __builtin_amdgcn_sched_barrier(0);
            // layer 3 + residual + SSE
            if (lane < 16) {
                int d = lane >> 2, q = lane & 3;
                float a3 = 0.f;
                #pragma unroll 4
                for (int k = q * 16; k < q * 16 + 16; ++k) a3 += scratch[k] * Wo3[k * 4 + d];
                a3 += __shfl_xor(a3, 1);
                a3 += __shfl_xor(a3, 2);
                if (q == 0) {
                    int jrow = j0 + r;
                    float xv = X[((b * 13 + tt) * 128 + jrow) * 4 + d];
                    float tg = X[((b * 13 + tt + 1) * 128 + jrow) * 4 + d];
                    float p = xv + a3 + bo3[d];
                    out[((b * TSTEPS + tt) * 128 + jrow) * 4 + d] = p;
                    float df = tg - p;
                    ssePart += df * df;
                }
            }
            asm volatile("s_waitcnt lgkmcnt(0)" ::: "memory");
            __builtin_amdgcn_sched_barrier(0);
        }
    }
    #pragma unroll
    for (int d = 1; d < 64; d <<= 1) ssePart += __shfl_xor(ssePart, d);
    if (lane == 0) rs[wave] = ssePart;
    __syncthreads();

    // ================= finalize loglik (last-arriver) =================
    if (tid == 0) {
        float s = 0.f;
        #pragma unroll
        for (int w = 0; w < 16; ++w) s += rs[w];
        atomicAdd(sseG, s);
        int prev = __hip_atomic_fetch_add(doneG, 1, __ATOMIC_ACQ_REL, __HIP_MEMORY_SCOPE_AGENT);
        if (prev == NBLK - 1) {
            float sse = __hip_atomic_load(sseG, __ATOMIC_RELAXED, __HIP_MEMORY_SCOPE_AGENT);
            float ls = lsg[0];
            float sigma = fminf(fmaxf(expf(ls), 1e-4f), 10.0f);
            float c = 0.5f * 4096.0f * logf(2.0f * 3.14159265358979323846f * sigma * sigma);
            float inv2s2 = 1.0f / (2.0f * sigma * sigma);
            out[B_ * TSTEPS * N_ * D_] = -(12.0f * c + sse * inv2s2);
        }
    }
}

extern "C" void kernel_launch(void* const* d_in, const int* in_sizes, int n_in,
                              void* d_out, int out_size, void* d_ws, size_t ws_size,
                              hipStream_t stream)
{
    const float* A    = (const float*)d_in[0];
    const float* X    = (const float*)d_in[1];
    const float* Wm1  = (const float*)d_in[2];
    const float* bm1  = (const float*)d_in[3];
    const float* Wm2  = (const float*)d_in[4];
    const float* bm2  = (const float*)d_in[5];
    const float* Wir  = (const float*)d_in[6];
    const float* bir  = (const float*)d_in[7];
    const float* Wii  = (const float*)d_in[8];
    const float* bii  = (const float*)d_in[9];
    const float* Win  = (const float*)d_in[10];
    const float* bin_ = (const float*)d_in[11];
    const float* Whr  = (const float*)d_in[12];
    const float* Whi  = (const float*)d_in[13];
    const float* Whh  = (const float*)d_in[14];
    const float* Wmr  = (const float*)d_in[15];
    const float* Wmi  = (const float*)d_in[16];
    const float* Wmn  = (const float*)d_in[17];
    const float* Wo1  = (const float*)d_in[18];
    const float* bo1  = (const float*)d_in[19];
    const float* Wo2  = (const float*)d_in[20];
    const float* bo2  = (const float*)d_in[21];
    const float* Wo3  = (const float*)d_in[22];
    const float* bo3  = (const float*)d_in[23];
    const float* lsg  = (const float*)d_in[24];
    uint32* wsU = (uint32*)d_ws;
    float* out = (float*)d_out;

    // zero counters / SSE / DONE each call (graph-replay safe)
    hipMemsetAsync((char*)d_ws + (size_t)CTRLu * 4, 0, CTRL_BYTES, stream);

    hipLaunchKernelGGL(fused, dim3(NBLK), dim3(1024), 0, stream,
                       A, X, Wm1, bm1, Wm2, bm2, Wir, bir, Wii, bii, Win, bin_,
                       Whr, Whi, Whh, Wmr, Wmi, Wmn, Wo1, bo1, Wo2, bo2, Wo3, bo3,
                       lsg, wsU, out);
}

// Round 24
// 198.940 us; speedup vs baseline: 1.4022x; 1.4022x over previous
//
#include <hip/hip_runtime.h>
#include <math.h>

// Problem constants
#define B_ 8
#define N_ 128
#define H_ 64
#define MH_ 128
#define D_ 4
#define TSTEPS 12
#define NBLK 256          // 1 block/CU x 256 CU -> all co-resident

typedef __attribute__((ext_vector_type(8))) short bf16x8;
typedef __attribute__((ext_vector_type(4))) float f32x4;
typedef __attribute__((ext_vector_type(4))) unsigned u32x4;
typedef unsigned uint32;

__device__ __forceinline__ float fast_tanh(float x) {
    float t = __builtin_amdgcn_exp2f(x * 2.8853900817779268f);
    return 1.0f - 2.0f * __builtin_amdgcn_rcpf(t + 1.0f);
}
__device__ __forceinline__ float fast_sigmoid(float x) {
    float t = __builtin_amdgcn_exp2f(x * -1.4426950408889634f);
    return __builtin_amdgcn_rcpf(1.0f + t);
}
__device__ __forceinline__ unsigned short f2bf(float x) {
    unsigned u = __builtin_bit_cast(unsigned, x);
    u += 0x7fffu + ((u >> 16) & 1u);   // RNE
    return (unsigned short)(u >> 16);
}
// packed bf16 pair: low16 = bf16(lo), high16 = bf16(hi); RNE (same as f2bf)
__device__ __forceinline__ uint32 cvtpk(float lo, float hi) {
    uint32 r;
    asm("v_cvt_pk_bf16_f32 %0, %1, %2" : "=v"(r) : "v"(lo), "v"(hi));
    return r;
}

// ---------------- workspace layout (uint32 units) ----------------
// P(t+1) in its own per-step buffer (t = 0..10): consumer addresses are first
// touched only after the producer's write-through lands -> plain coalesced
// loads are fresh, no fences. Producers publish via relaxed agent-scope
// (write-through) atomic stores. Sync per (batch, 32-row i-window),
// ONE global signal per producing block per step (LDS last-arriver).
constexpr int PB_STRIDE = 65536;              // [8][128][64] uints per step-buffer
constexpr int CTRLu = 11 * PB_STRIDE;         // cnt[8][4] @ stride 16; SSE @ +512; DONE @ +513
constexpr int CTRL_BYTES = (32 * 16 + 2) * 4;

__global__ __launch_bounds__(1024, 4) void fused(
    const float* __restrict__ A, const float* __restrict__ X,
    const float* __restrict__ Wm1, const float* __restrict__ bm1,
    const float* __restrict__ Wm2, const float* __restrict__ bm2,
    const float* __restrict__ Wir, const float* __restrict__ bir,
    const float* __restrict__ Wii, const float* __restrict__ bii,
    const float* __restrict__ Win, const float* __restrict__ bin_,
    const float* __restrict__ Whr, const float* __restrict__ Whi, const float* __restrict__ Whh,
    const float* __restrict__ Wmr, const float* __restrict__ Wmi, const float* __restrict__ Wmn,
    const float* __restrict__ Wo1, const float* __restrict__ bo1,
    const float* __restrict__ Wo2, const float* __restrict__ bo2,
    const float* __restrict__ Wo3, const float* __restrict__ bo3,
    const float* __restrict__ lsg,
    uint32* wsU, float* __restrict__ out)
{
    __shared__ __align__(16) unsigned short wm2f[8192];  // 16 KB Wm2 MFMA B-fragments
    __shared__ __align__(16) float WamL[12288];          // 48 KB [k][192] Wmr|Wmi|Wmn
    __shared__ __align__(16) float Wm1L[16384];          // 64 KB [k][128] (full Wm1)
    __shared__ float Qj[4][128], apRow[4][128], rs[128], bmS[128];
    __shared__ float aggbuf[4][4][64];                   // rowsum partials at init / MLP scratch
    __shared__ float sAgg[4][64], sAm[4][192], sHP[4][192];
    __shared__ float sHist[TSTEPS][4][64];               // 12 KB: h(t) history
    __shared__ float sX[4][4];
    __shared__ int pubCnt;                               // LDS publish coordinator

    const int bid = blockIdx.x, tid = threadIdx.x;
    const int b = bid >> 5;                 // batch
    const int j0 = (bid & 31) << 2;         // block owns rows j0..j0+3
    const int wave = tid >> 6, lane = tid & 63;
    const int jj = wave >> 2;               // which of the 4 j-rows (phase A)
    const int wvj = wave & 3;               // i-window index (phase A)
    const int l15 = lane & 15, g = lane >> 4;
    const int myI0 = wvj * 32;

    int*   cntBase = (int*)(wsU + CTRLu);
    int*   cntW    = cntBase + (b * 4 + wvj) * 16;          // window this wave CONSUMES
    int*   cntPub  = cntBase + (b * 4 + (j0 >> 5)) * 16;    // window this block PRODUCES
    float* sseG    = (float*)(wsU + CTRLu + 512);
    int*   doneG   = (int*)(wsU + CTRLu + 513);
    const float* Ab = A + b * 16384;

    // ================= init (fully block-local) =================
    {   // rowsum_i: 1024 threads, 8 chunks of 16 j each
        int i = tid & 127, q = tid >> 7;
        float part = 0.f;
        int jlo = q * 16;
        #pragma unroll 4
        for (int j2 = jlo; j2 < jlo + 16; ++j2)
            if (j2 != i)
                part += fast_sigmoid(0.5f * (Ab[i * 128 + j2] + Ab[j2 * 128 + i]));
        ((float*)aggbuf)[q * 128 + i] = part;   // [8][128] view
    }
    __syncthreads();
    if (tid < 128) {
        const float* f = (const float*)aggbuf;
        float s = 0.f;
        #pragma unroll
        for (int c = 0; c < 8; ++c) s += f[c * 128 + tid];
        rs[tid] = s + 1e-6f;
        bmS[tid] = bm1[tid];
    }
    __syncthreads();
    if (tid < 512) {    // apRow[h][i] = s(i, j0+h) / rowsum_i
        int i = tid & 127, h = tid >> 7, jc = j0 + h;
        float s = (i == jc) ? 0.f
                : fast_sigmoid(0.5f * (Ab[i * 128 + jc] + Ab[jc * 128 + i]));
        apRow[h][i] = s / rs[i];
    }
    for (int idx = tid; idx < 8192; idx += 1024) {   // pack Wm2 -> bf16 B-fragments
        int kt = idx >> 11, nt = (idx >> 9) & 3, ln = (idx >> 3) & 63, e = idx & 7;
        int k = kt * 32 + (ln >> 4) * 8 + e, n = nt * 16 + (ln & 15);
        wm2f[idx] = f2bf(Wm2[k * 64 + n]);
    }
    for (int idx = tid; idx < 12288; idx += 1024) {  // WamL[k*192+c] fp32
        int k = idx / 192, c = idx % 192;
        WamL[idx] = ((c < 64) ? Wmr : (c < 128) ? Wmi : Wmn)[k * 64 + (c & 63)];
    }
    for (int idx = tid; idx < 16384; idx += 1024)    // Wm1L direct copy [128][128]
        Wm1L[idx] = Wm1[idx];
    if (tid < 512) Qj[tid >> 7][tid & 127] = 0.f;
    if (tid < 768) sHP[tid / 192][tid % 192] = 0.f;
    if (tid < 256) sAgg[tid >> 6][tid & 63] = 0.f;   // atomics accumulate into zeroed sAgg
    if (tid == 0) pubCnt = 0;
    __syncthreads();

    // ================= time loop =================
    for (int t = 0; t < TSTEPS; ++t) {
        const uint32* Psrc = wsU + (t - 1) * PB_STRIDE + b * 8192;  // valid for t>0
        if (t > 0) {
            const int target = 8 * t;   // 8 producing blocks x 1 signal per window
            int guard = 0;
            while (__hip_atomic_load(cntW, __ATOMIC_RELAXED, __HIP_MEMORY_SCOPE_AGENT) < target
                   && guard < (1 << 20)) {
                __builtin_amdgcn_s_sleep(1);
                ++guard;
            }
            __builtin_amdgcn_fence(__ATOMIC_ACQUIRE, "workgroup");  // no hoisting of P loads
        }

        // ===== phase A: msg = tanh(tanh(P_i + Q_j) @ Wm2 + bm2), A-weighted agg =====
        f32x4 acc[2][4];
        #pragma unroll
        for (int mt = 0; mt < 2; ++mt)
            #pragma unroll
            for (int nt = 0; nt < 4; ++nt) {
                f32x4 z = {0.f, 0.f, 0.f, 0.f};
                acc[mt][nt] = z;
            }
        #pragma unroll
        for (int kt = 0; kt < 4; ++kt) {
            int k0 = kt * 32 + g * 8;
            bf16x8 bf[4];
            #pragma unroll
            for (int nt = 0; nt < 4; ++nt)
                bf[nt] = *(const bf16x8*)&wm2f[((kt * 4 + nt) * 64 + lane) << 3];
            f32x4 qa = *(const f32x4*)&Qj[jj][k0];
            f32x4 qb = *(const f32x4*)&Qj[jj][k0 + 4];
            bf16x8 af[2];
            #pragma unroll
            for (int mt = 0; mt < 2; ++mt) {
                int row = myI0 + mt * 16 + l15;
                float pe[8];
                if (t > 0) {    // direct 16B load from the fresh per-step buffer
                    u32x4 pv = *(const u32x4*)(Psrc + row * 64 + kt * 16 + g * 4);
                    #pragma unroll
                    for (int c = 0; c < 4; ++c) {
                        pe[2 * c]     = __builtin_bit_cast(float, pv[c] << 16);
                        pe[2 * c + 1] = __builtin_bit_cast(float, pv[c] & 0xFFFF0000u);
                    }
                } else {        // P(0) rows are all bm1 (h0 = 0)
                    #pragma unroll
                    for (int e = 0; e < 8; ++e) pe[e] = bmS[k0 + e];
                }
                float tv[8];
                #pragma unroll
                for (int e = 0; e < 4; ++e) {
                    tv[e]     = fast_tanh(pe[e] + qa[e]);
                    tv[4 + e] = fast_tanh(pe[4 + e] + qb[e]);
                }
                u32x4 aw;
                aw[0] = cvtpk(tv[0], tv[1]); aw[1] = cvtpk(tv[2], tv[3]);
                aw[2] = cvtpk(tv[4], tv[5]); aw[3] = cvtpk(tv[6], tv[7]);
                af[mt] = __builtin_bit_cast(bf16x8, aw);
            }
            #pragma unroll
            for (int mt = 0; mt < 2; ++mt)
                #pragma unroll
                for (int nt = 0; nt < 4; ++nt)
                    acc[mt][nt] = __builtin_amdgcn_mfma_f32_16x16x32_bf16(af[mt], bf[nt], acc[mt][nt], 0, 0, 0);
        }
        {
            float bmv[4];
            #pragma unroll
            for (int nt = 0; nt < 4; ++nt) bmv[nt] = bm2[nt * 16 + l15];
            float pagg[4] = {0.f, 0.f, 0.f, 0.f};
            #pragma unroll
            for (int mt = 0; mt < 2; ++mt) {
                float w[4];
                #pragma unroll
                for (int v = 0; v < 4; ++v) w[v] = apRow[jj][myI0 + mt * 16 + g * 4 + v];
                #pragma unroll
                for (int nt = 0; nt < 4; ++nt)
                    #pragma unroll
                    for (int v = 0; v < 4; ++v)
                        pagg[nt] += w[v] * fast_tanh(acc[mt][nt][v] + bmv[nt]);
            }
            #pragma unroll
            for (int nt = 0; nt < 4; ++nt) {
                pagg[nt] += __shfl_xor(pagg[nt], 16);
                pagg[nt] += __shfl_xor(pagg[nt], 32);
            }
            if (lane < 16)
                #pragma unroll
                for (int nt = 0; nt < 4; ++nt)
                    atomicAdd(&sAgg[jj][nt * 16 + lane], pagg[nt]);
        }
        __syncthreads();   // b1: sAgg complete

        // ===== am GEMV (6 waves) + X load on idle lanes =====
        if (tid < 384) {
            int pr2 = tid / 192, c = tid % 192;
            int ar0 = pr2 * 2, ar1 = ar0 + 1;
            float a0 = 0.f, a1 = 0.f;
            #pragma unroll 8
            for (int k = 0; k < 64; ++k) {
                float w = WamL[k * 192 + c];
                a0 += sAgg[ar0][k] * w; a1 += sAgg[ar1][k] * w;
            }
            sAm[ar0][c] = a0; sAm[ar1][c] = a1;
        } else if (tid >= 960 && tid < 976) {   // X load
            int q = tid - 960;
            int r = q >> 2, d = q & 3, jrow = j0 + r;
            sX[r][d] = X[((b * 13 + t) * 128 + jrow) * 4 + d];
        }
        __syncthreads();   // b2: sAm + sX ready

        if (tid < 256) {   // GRU gates, one row per 64-thread group; h -> history
            int r = tid >> 6, o = tid & 63;
            float xr = bir[o], xi = bii[o], xn = bin_[o];
            #pragma unroll
            for (int d = 0; d < 4; ++d) {
                float xv = sX[r][d];
                xr += xv * Wir[d * 64 + o];
                xi += xv * Wii[d * 64 + o];
                xn += xv * Win[d * 64 + o];
            }
            float hprev = (t > 0) ? sHist[t - 1][r][o] : 0.f;
            float rr = fast_sigmoid(xr + sHP[r][o]       + sAm[r][o]);
            float ig = fast_sigmoid(xi + sHP[r][64 + o]  + sAm[r][64 + o]);
            float nn = fast_tanh  (xn + rr * sHP[r][128 + o] + sAm[r][128 + o]);
            sHist[t][r][o] = (1.0f - ig) * nn + ig * hprev;
        }
        __syncthreads();   // b3: h(t) ready

        // ===== GEMV phase: P' (8 waves, k-split) / Q' (2 waves) / HP' (6 waves) =====
        if (t < TSTEPS - 1) {
            if (wave < 4 || (wave >= 8 && wave < 12)) {       // P' k-split + publish
                int p = (wave >= 8) ? 1 : 0;
                int wl = wave & 3;
                int rr0 = p * 2, rr1 = rr0 + 1;
                int o = wl * 32 + (lane & 31);                // 0..127
                int klo = (lane >> 5) << 5;                   // 0 or 32
                float a0 = 0.f, a1 = 0.f;
                #pragma unroll 8
                for (int k = klo; k < klo + 32; ++k) {
                    float w = Wm1L[k * 128 + o];
                    a0 += sHist[t][rr0][k] * w; a1 += sHist[t][rr1][k] * w;
                }
                a0 += __shfl_xor(a0, 32);
                a1 += __shfl_xor(a1, 32);
                if (lane < 32) {
                    a0 += bmS[o]; a1 += bmS[o];
                    uint32 u0 = cvtpk(a0, __shfl_down(a0, 1));
                    uint32 u1 = cvtpk(a1, __shfl_down(a1, 1));
                    if ((o & 1) == 0) {
                        uint32* base = wsU + t * PB_STRIDE + b * 8192;
                        __hip_atomic_store(base + (j0 + rr0) * 64 + (o >> 1), u0,
                                           __ATOMIC_RELAXED, __HIP_MEMORY_SCOPE_AGENT);
                        __hip_atomic_store(base + (j0 + rr1) * 64 + (o >> 1), u1,
                                           __ATOMIC_RELAXED, __HIP_MEMORY_SCOPE_AGENT);
                    }
                }
                asm volatile("s_waitcnt vmcnt(0)" ::: "memory");   // wave's stores landed
                if (lane == 0) {
                    int prev = __hip_atomic_fetch_add(&pubCnt, 1, __ATOMIC_RELAXED,
                                                      __HIP_MEMORY_SCOPE_WORKGROUP);
                    if (prev == 8 * t + 7)   // last of 8 P' waves this step
                        __hip_atomic_fetch_add(cntPub, 1, __ATOMIC_RELAXED,
                                               __HIP_MEMORY_SCOPE_AGENT);
                }
            } else if (wave == 4 || wave == 12) {             // Q' (2 outputs/thread)
                int p = (wave == 12) ? 1 : 0;
                int rr0 = p * 2, rr1 = rr0 + 1;
                #pragma unroll
                for (int h2 = 0; h2 < 2; ++h2) {
                    int oo = lane + h2 * 64;
                    float a0 = 0.f, a1 = 0.f;
                    #pragma unroll 8
                    for (int k = 0; k < 64; ++k) {
                        float w = Wm1L[(64 + k) * 128 + oo];
                        a0 += sHist[t][rr0][k] * w; a1 += sHist[t][rr1][k] * w;
                    }
                    Qj[rr0][oo] = a0; Qj[rr1][oo] = a1;
                }
                if (wave == 12) {   // zero sAgg for t+1
                    #pragma unroll
                    for (int r = 0; r < 4; ++r) sAgg[r][lane] = 0.f;
                }
            } else {                                          // HP': waves 5-7 / 13-15
                int p = (wave >= 13) ? 1 : 0;
                int rr0 = p * 2, rr1 = rr0 + 1;
                int c = p ? (tid - 832) : (tid - 320);        // 0..191
                const float* W = (c < 64) ? Whr : (c < 128) ? Whi : Whh;
                int oc = c & 63;
                float a0 = 0.f, a1 = 0.f;
                #pragma unroll 8
                for (int k = 0; k < 64; ++k) {
                    float w = W[k * 64 + oc];
                    a0 += sHist[t][rr0][k] * w; a1 += sHist[t][rr1][k] * w;
                }
                sHP[rr0][c] = a0; sHP[rr1][c] = a1;
            }
        }
        __syncthreads();   // b4
    }

    // ================= deferred output MLP + SSE (off the recurrence path) =================
    float ssePart = 0.f;
    {
        float* scratch = &((float*)aggbuf)[wave * 64];   // [16][64] per-wave view
        #pragma unroll
        for (int inst = 0; inst < 3; ++inst) {
            int idx = wave + (inst << 4);      // 0..47 = (t, r)
            int tt = idx >> 2, r = idx & 3;
            // layer 1
            float a = bo1[lane];
            #pragma unroll 8
            for (int k = 0; k < 64; ++k) a += sHist[tt][r][k] * Wo1[k * 64 + lane];
            scratch[lane] = fmaxf(a, 0.f);
            asm volatile("s_waitcnt lgkmcnt(0)" ::: "memory");
            __builtin_amdgcn_sched_barrier(0);
            // layer 2
            float a2 = bo2[lane];
            #pragma unroll 8
            for (int k = 0; k < 64; ++k) a2 += scratch[k] * Wo2[k * 64 + lane];
            scratch[lane] = fmaxf(a2, 0.f);
            asm volatile("s_waitcnt lgkmcnt(0)" ::: "memory");
            __builtin_amdgcn_sched_barrier(0);
            // layer 3 + residual + SSE
            if (lane < 16) {
                int d = lane >> 2, q = lane & 3;
                float a3 = 0.f;
                #pragma unroll 4
                for (int k = q * 16; k < q * 16 + 16; ++k) a3 += scratch[k] * Wo3[k * 4 + d];
                a3 += __shfl_xor(a3, 1);
                a3 += __shfl_xor(a3, 2);
                if (q == 0) {
                    int jrow = j0 + r;
                    float xv = X[((b * 13 + tt) * 128 + jrow) * 4 + d];
                    float tg = X[((b * 13 + tt + 1) * 128 + jrow) * 4 + d];
                    float p = xv + a3 + bo3[d];
                    out[((b * TSTEPS + tt) * 128 + jrow) * 4 + d] = p;
                    float df = tg - p;
                    ssePart += df * df;
                }
            }
            asm volatile("s_waitcnt lgkmcnt(0)" ::: "memory");
            __builtin_amdgcn_sched_barrier(0);
        }
    }
    #pragma unroll
    for (int d = 1; d < 64; d <<= 1) ssePart += __shfl_xor(ssePart, d);
    if (lane == 0) rs[wave] = ssePart;
    __syncthreads();

    // ================= finalize loglik (last-arriver) =================
    if (tid == 0) {
        float s = 0.f;
        #pragma unroll
        for (int w = 0; w < 16; ++w) s += rs[w];
        atomicAdd(sseG, s);
        int prev = __hip_atomic_fetch_add(doneG, 1, __ATOMIC_ACQ_REL, __HIP_MEMORY_SCOPE_AGENT);
        if (prev == NBLK - 1) {
            float sse = __hip_atomic_load(sseG, __ATOMIC_RELAXED, __HIP_MEMORY_SCOPE_AGENT);
            float ls = lsg[0];
            float sigma = fminf(fmaxf(expf(ls), 1e-4f), 10.0f);
            float c = 0.5f * 4096.0f * logf(2.0f * 3.14159265358979323846f * sigma * sigma);
            float inv2s2 = 1.0f / (2.0f * sigma * sigma);
            out[B_ * TSTEPS * N_ * D_] = -(12.0f * c + sse * inv2s2);
        }
    }
}

extern "C" void kernel_launch(void* const* d_in, const int* in_sizes, int n_in,
                              void* d_out, int out_size, void* d_ws, size_t ws_size,
                              hipStream_t stream)
{
    const float* A    = (const float*)d_in[0];
    const float* X    = (const float*)d_in[1];
    const float* Wm1  = (const float*)d_in[2];
    const float* bm1  = (const float*)d_in[3];
    const float* Wm2  = (const float*)d_in[4];
    const float* bm2  = (const float*)d_in[5];
    const float* Wir  = (const float*)d_in[6];
    const float* bir  = (const float*)d_in[7];
    const float* Wii  = (const float*)d_in[8];
    const float* bii  = (const float*)d_in[9];
    const float* Win  = (const float*)d_in[10];
    const float* bin_ = (const float*)d_in[11];
    const float* Whr  = (const float*)d_in[12];
    const float* Whi  = (const float*)d_in[13];
    const float* Whh  = (const float*)d_in[14];
    const float* Wmr  = (const float*)d_in[15];
    const float* Wmi  = (const float*)d_in[16];
    const float* Wmn  = (const float*)d_in[17];
    const float* Wo1  = (const float*)d_in[18];
    const float* bo1  = (const float*)d_in[19];
    const float* Wo2  = (const float*)d_in[20];
    const float* bo2  = (const float*)d_in[21];
    const float* Wo3  = (const float*)d_in[22];
    const float* bo3  = (const float*)d_in[23];
    const float* lsg  = (const float*)d_in[24];
    uint32* wsU = (uint32*)d_ws;
    float* out = (float*)d_out;

    // zero counters / SSE / DONE each call (graph-replay safe)
    hipMemsetAsync((char*)d_ws + (size_t)CTRLu * 4, 0, CTRL_BYTES, stream);

    hipLaunchKernelGGL(fused, dim3(NBLK), dim3(1024), 0, stream,
                       A, X, Wm1, bm1, Wm2, bm2, Wir, bir, Wii, bii, Win, bin_,
                       Whr, Whi, Whh, Wmr, Wmi, Wmn, Wo1, bo1, Wo2, bo2, Wo3, bo3,
                       lsg, wsU, out);
}